// Round 11
// baseline (266.986 us; speedup 1.0000x reference)
//
#include <hip/hip_runtime.h>

// ---------------------------------------------------------------------------
// Soft decision tree forward (all-f16 pipeline), round 11.
//   d = sigmoid(X @ T^T); leaf probs = depth-10 path products;
//   out = softmax(probs @ L)
//
// Round-11: the round-10 mechanism (wave-private B operand fragment-packed in
// global -> coalesced direct-to-register loads) applied to BOTH GEMMs, plus
// LDS-broadcast of the shared A operand:
//  - prep_tp packs thresholds Th into MFMA-fragment order (Bpk1, 2 MiB).
//  - gemm1: LDS-A 32KB dbuf (r8-proven staging+swizzle) + direct-reg B dbuf;
//    1 barrier + counted vm(4) per 32-K step (was 8 barriers / 64-K tile).
//  - gemm2sm: A broadcast via 4KB/step LDS dbuf (kills the 16x-redundant
//    per-wave A fetch that made it L1-request-bound) + direct-reg B dbuf.
// Fragment layout (proven): elem(lane=kg*16+mr, j) = Op[blk*16+mr][kt*32+kg*8+j]
//   pack index: [(blk16*32 + kt)*64 + lane]*8 + j
// Arithmetic order unchanged everywhere -> absmax canary 0.0004882812.
// ---------------------------------------------------------------------------

typedef unsigned short u16;
typedef unsigned short u16x8 __attribute__((ext_vector_type(8)));
typedef _Float16 f16;
typedef _Float16 f16x8 __attribute__((ext_vector_type(8)));
typedef float f32x4 __attribute__((ext_vector_type(4)));

#define BATCH 32768
#define DIM   1024
#define NPAD  1024

#define WAIT_VM(N) asm volatile("s_waitcnt vmcnt(" #N ")" ::: "memory")
#define BARRIER()  asm volatile("s_barrier" ::: "memory")

// ---- f16 helpers ----
__device__ __forceinline__ u16 f2h(float f) {
    union { f16 h; u16 u; } v; v.h = (f16)f; return v.u;
}
__device__ __forceinline__ float h2f(u16 u) {
    union { u16 u; f16 h; } v; v.u = u; return (float)v.h;
}

// ---- async global->LDS (dest = wave-uniform base + lane*size) ----
__device__ __forceinline__ void gl16(const u16* g, char* l) {
    __builtin_amdgcn_global_load_lds(
        (const __attribute__((address_space(1))) unsigned int*)g,
        (__attribute__((address_space(3))) unsigned int*)l, 16, 0, 0);
}
__device__ __forceinline__ void gl4(const u16* g, char* l) {
    __builtin_amdgcn_global_load_lds(
        (const __attribute__((address_space(1))) unsigned int*)g,
        (__attribute__((address_space(3))) unsigned int*)l, 4, 0, 0);
}

#define MFMA16(a, b, c) __builtin_amdgcn_mfma_f32_16x16x32_f16(a, b, c, 0, 0, 0)

// ---------------------------------------------------------------------------
// prep: X f32 -> Xh f16 (frozen)
// ---------------------------------------------------------------------------
__global__ __launch_bounds__(256) void prep_x(const float4* __restrict__ x4,
                                              u16* __restrict__ xh, int n4) {
    int stride = gridDim.x * blockDim.x;
    for (int i = blockIdx.x * blockDim.x + threadIdx.x; i < n4; i += stride) {
        float4 v = x4[i];
        *(ushort4*)&xh[(size_t)i * 4] =
            make_ushort4(f2h(v.x), f2h(v.y), f2h(v.z), f2h(v.w));
    }
}

// ---------------------------------------------------------------------------
// prep: thresholds (1023x1024 f32) -> Bpk1 fragment-packed f16 (node row 1023=0)
// Bpk1[((n16*32 + kt)*64 + lane)*8 + j] = T[n16*16 + mr][kt*32 + kg*8 + j]
// ---------------------------------------------------------------------------
__global__ __launch_bounds__(256) void prep_tp(const float* __restrict__ t,
                                               u16* __restrict__ Bpk1) {
    int o = (blockIdx.x * 256 + threadIdx.x) * 4;
    int n16  = o >> 14;
    int kt   = (o >> 9) & 31;
    int lane = (o >> 3) & 63;
    int j0   = o & 7;
    int mr = lane & 15, kg = lane >> 4;
    int node = n16 * 16 + mr;
    int k0  = kt * 32 + kg * 8 + j0;
    ushort4 v = make_ushort4(0, 0, 0, 0);
    if (node < 1023) {
        const float* src = t + (size_t)node * 1024 + k0;
        v.x = f2h(src[0]); v.y = f2h(src[1]);
        v.z = f2h(src[2]); v.w = f2h(src[3]);
    }
    *(ushort4*)&Bpk1[o] = v;
}

// ---------------------------------------------------------------------------
// prep: L (1024x1024 f32, [leaf][out]) -> BpkL fragment-packed f16 (frozen r10)
// ---------------------------------------------------------------------------
__global__ __launch_bounds__(256) void prep_lt(const float* __restrict__ L,
                                               u16* __restrict__ BpkL) {
    int o = (blockIdx.x * 256 + threadIdx.x) * 4;
    int b16  = o >> 14;
    int kt   = (o >> 9) & 31;
    int lane = (o >> 3) & 63;
    int j0   = o & 7;
    int mr = lane & 15, kg = lane >> 4;
    int col = b16 * 16 + mr;
    int k0  = kt * 32 + kg * 8 + j0;
    ushort4 v;
    v.x = f2h(L[(size_t)(k0 + 0) * 1024 + col]);
    v.y = f2h(L[(size_t)(k0 + 1) * 1024 + col]);
    v.z = f2h(L[(size_t)(k0 + 2) * 1024 + col]);
    v.w = f2h(L[(size_t)(k0 + 3) * 1024 + col]);
    *(ushort4*)&BpkL[o] = v;
}

// bijective XCD swizzle: 512 blocks, 64 per XCD.
__device__ __forceinline__ void block_map(int bid, int& rb, int& cb) {
    int lid = (bid & 7) * 64 + (bid >> 3);
    rb = (lid >> 2) << 8;
    cb = (lid & 3) << 8;
}

// ---------------------------------------------------------------------------
// GEMM1: d = sigmoid(X @ T^T) -> dval f16.
// 256x256 tile, 8 waves (wm=wid>>2: rows wm*128; wn=wid&3: cols wn*64).
// BK=32, 32 steps. A (Xh) via LDS 2x16KB dbuf, r8-proven staging (row-XOR
// swizzle key=(row&3) on 16B slots, pre-swizzled source) . B (Bpk1) coalesced
// direct-to-reg, one-step-prefetch dbuf (unroll-2 static names).
// Per step: stgA(kt+1) [2 gl16]; b(kt+1) [4x 1KB dwordx4]; ds_read a[8];
// 32 MFMA b(kt); vm(4) [A landed, b in flight]; barrier.
// ---------------------------------------------------------------------------
__global__ __launch_bounds__(512, 2) void gemm1_8p(
    const u16* __restrict__ Xh, const u16* __restrict__ Bpk1,
    u16* __restrict__ dval)
{
    __shared__ __align__(16) char lds[32768];
    const int t = threadIdx.x, wid = t >> 6, lane = t & 63;
    const int wm = wid >> 2, wn = wid & 3;
    const int mr = lane & 15, kg = lane >> 4;
    int rb, cb;
    block_map(blockIdx.x, rb, cb);

    // A staging source (pre-swizzled; r8-proven): row = t>>2, chunk = t&3
    const unsigned arow = (unsigned)(t >> 2);
    const unsigned sA0 = (unsigned)(rb + (int)arow) * 1024u +
                         8u * (unsigned)((t & 3) ^ ((int)arow & 3));

    // a ds_read offsets: row = wm*128 + m*16 + mr; key = (mr&3)<<4
    unsigned offA[8];
#pragma unroll
    for (int m = 0; m < 8; ++m) {
        unsigned row = (unsigned)(wm * 128 + m * 16 + mr);
        offA[m] = row * 64u + (((unsigned)kg << 4) ^ (((unsigned)(mr & 3)) << 4));
    }

    // b packed bases: col-16-block = cb/16 + wn*4 + n
    const u16* bbase[4];
#pragma unroll
    for (int n = 0; n < 4; ++n)
        bbase[n] = Bpk1 + (size_t)((cb >> 4) + wn * 4 + n) * 16384 + (unsigned)lane * 8u;

    f32x4 acc[8][4];
#pragma unroll
    for (int m = 0; m < 8; ++m)
#pragma unroll
        for (int n = 0; n < 4; ++n) acc[m][n] = (f32x4){0.f, 0.f, 0.f, 0.f};

    auto stgA = [&](int kt) {
        char* dst = lds + (kt & 1) * 16384 + t * 16;
        const u16* g = Xh + sA0 + (unsigned)kt * 32u;
        gl16(g, dst);
        gl16(g + 131072u, dst + 8192);   // rows +128
    };

    f16x8 bA[4], bB[4];

    // prologue: stage A(0), load b(0); drain A only (b stays in flight)
    stgA(0);
#pragma unroll
    for (int n = 0; n < 4; ++n) bA[n] = *(const f16x8*)(bbase[n]);
    WAIT_VM(4);
    BARRIER();

    auto step = [&](int kt, f16x8 (&bu)[4], f16x8 (&bl)[4]) {
        if (kt + 1 < 32) {
            stgA(kt + 1);
#pragma unroll
            for (int n = 0; n < 4; ++n)
                bl[n] = *(const f16x8*)(bbase[n] + (unsigned)(kt + 1) * 512u);
        }
        char* LA = lds + (kt & 1) * 16384;
        f16x8 a[8];
#pragma unroll
        for (int m = 0; m < 8; ++m) a[m] = *(const f16x8*)(LA + offA[m]);
        __builtin_amdgcn_s_setprio(1);
#pragma unroll
        for (int m = 0; m < 8; ++m)
#pragma unroll
            for (int n = 0; n < 4; ++n)
                acc[m][n] = MFMA16(a[m], bu[n], acc[m][n]);
        __builtin_amdgcn_s_setprio(0);
        if (kt + 1 < 32) {
            WAIT_VM(4);   // A(kt+1) landed; b(kt+1) still in flight
            BARRIER();
        }
    };

#pragma unroll 1
    for (int k2 = 0; k2 < 16; ++k2) {
        step(2 * k2, bA, bB);
        step(2 * k2 + 1, bB, bA);
    }

    // epilogue: sigmoid -> d f16
    const int fq = kg * 4;
#pragma unroll
    for (int m = 0; m < 8; ++m)
#pragma unroll
        for (int j = 0; j < 4; ++j) {
            int grow = rb + wm * 128 + m * 16 + fq + j;
#pragma unroll
            for (int n = 0; n < 4; ++n) {
                int gcol = cb + wn * 64 + n * 16 + mr;
                float s = acc[m][n][j];
                float d = 1.0f / (1.0f + __expf(-s));
                dval[(size_t)grow * NPAD + gcol] = f2h(d);
            }
        }
}

// ---------------------------------------------------------------------------
// tree expansion (frozen r10): writes Apk fragment-packed
// ---------------------------------------------------------------------------
__global__ __launch_bounds__(256) void probs_kernel(const u16* __restrict__ dval,
                                                    u16* __restrict__ Apk) {
    const int t = threadIdx.x, w = t >> 6, l = t & 63;
    const int row = (blockIdx.x << 2) + w;
    const u16* dp = dval + (size_t)row * NPAD;

    float prod = 1.0f;
#pragma unroll
    for (int lev = 0; lev < 6; lev++) {
        int node = (1 << lev) - 1 + (l >> (6 - lev));
        int bit  = (l >> (5 - lev)) & 1;
        float v = h2f(dp[node]);
        prod *= bit ? (1.0f - v) : v;
    }
    float d6 = h2f(dp[63 + l]);
    float d7[2], d8[4], d9[8];
#pragma unroll
    for (int j = 0; j < 2; j++) d7[j] = h2f(dp[127 + 2 * l + j]);
#pragma unroll
    for (int j = 0; j < 4; j++) d8[j] = h2f(dp[255 + 4 * l + j]);
#pragma unroll
    for (int j = 0; j < 8; j++) d9[j] = h2f(dp[511 + 8 * l + j]);

    u16 outv[16];
#pragma unroll
    for (int j = 0; j < 16; j++) {
        float f6 = (j >> 3) ? (1.0f - d6) : d6;
        float v7 = d7[j >> 3];  float f7 = ((j >> 2) & 1) ? (1.0f - v7) : v7;
        float v8 = d8[j >> 2];  float f8 = ((j >> 1) & 1) ? (1.0f - v8) : v8;
        float v9 = d9[j >> 1];  float f9 = (j & 1) ? (1.0f - v9) : v9;
        outv[j] = f2h(prod * f6 * f7 * f8 * f9);
    }

    const int rb64 = row >> 6, m = (row >> 4) & 3, mrr = row & 15;
    const int kg0 = (l & 1) * 2;
    u16* base = Apk + (size_t)rb64 * 65536 + (l >> 1) * 2048 + m * 512;
    *(u16x8*)(base + (kg0 * 16 + mrr) * 8) =
        (u16x8){outv[0], outv[1], outv[2], outv[3], outv[4], outv[5], outv[6], outv[7]};
    *(u16x8*)(base + ((kg0 + 1) * 16 + mrr) * 8) =
        (u16x8){outv[8], outv[9], outv[10], outv[11], outv[12], outv[13], outv[14], outv[15]};
}

// ---------------------------------------------------------------------------
// FUSED GEMM2 + SOFTMAX, round 11: A broadcast via 4KB/step LDS dbuf (one gl4
// per thread, coalesced source; kills the 16x-redundant per-wave A fetch);
// B (BpkL) coalesced direct-to-reg one-step-prefetch dbuf. Block = 64 full
// rows, 1024 threads / 16 waves; wave wid owns cols wid*64: acc[4][4].
// Per step: stgA(kt+1); b(kt+1) [4x 1KB]; ds_read a[4] (linear, conflict-
// free); 16 MFMA b(kt); vm(4); barrier. Softmax epilogue via same 8KB LDS.
// ---------------------------------------------------------------------------
__global__ __launch_bounds__(1024, 1) void gemm2sm(
    const u16* __restrict__ Apk, const u16* __restrict__ BpkL,
    float* __restrict__ out)
{
    __shared__ __align__(16) char lds[8192];
    const int t = threadIdx.x, wid = t >> 6, lane = t & 63;
    const int mr = lane & 15, kg = lane >> 4;

    const u16* abase = Apk + (size_t)blockIdx.x * 65536;
    const u16* bbase = BpkL + (size_t)(wid * 4) * 16384 + (unsigned)lane * 8u;
    const unsigned aoff = (unsigned)lane * 16u;

    f32x4 acc[4][4];
#pragma unroll
    for (int m = 0; m < 4; ++m)
#pragma unroll
        for (int n = 0; n < 4; ++n) acc[m][n] = (f32x4){0.f, 0.f, 0.f, 0.f};

    auto stgA = [&](int kt) {
        char* dst = lds + (kt & 1) * 4096 + t * 4;
        gl4(abase + (unsigned)kt * 2048u + (unsigned)t * 2u, dst);
    };

    f16x8 bA[4], bB[4];

    // prologue: stage A(0), load b(0); drain A only
    stgA(0);
#pragma unroll
    for (int n = 0; n < 4; ++n) bA[n] = *(const f16x8*)(bbase + n * 16384);
    WAIT_VM(4);
    BARRIER();

    auto step = [&](int kt, f16x8 (&bu)[4], f16x8 (&bl)[4]) {
        if (kt + 1 < 32) {
            stgA(kt + 1);
#pragma unroll
            for (int n = 0; n < 4; ++n)
                bl[n] = *(const f16x8*)(bbase + n * 16384 + (unsigned)(kt + 1) * 512u);
        }
        char* sa = lds + (kt & 1) * 4096;
        f16x8 a[4];
#pragma unroll
        for (int m = 0; m < 4; ++m) a[m] = *(const f16x8*)(sa + m * 1024 + aoff);
        __builtin_amdgcn_s_setprio(1);
#pragma unroll
        for (int m = 0; m < 4; ++m)
#pragma unroll
            for (int n = 0; n < 4; ++n)
                acc[m][n] = MFMA16(a[m], bu[n], acc[m][n]);
        __builtin_amdgcn_s_setprio(0);
        if (kt + 1 < 32) {
            WAIT_VM(4);   // A(kt+1) landed; b(kt+1) still in flight
            BARRIER();
        }
    };

#pragma unroll 1
    for (int k2 = 0; k2 < 16; ++k2) {
        step(2 * k2, bA, bB);
        step(2 * k2 + 1, bB, bA);
    }

    // ---------------- in-register softmax over full rows ----------------
    // thread rows: r(m,j) = m*16 + kg*4 + j; cols: wid*64 + n*16 + mr
    __syncthreads();                      // all LDS slot reads done
    float* red  = (float*)lds;            // [64][16] max
    float* red2 = (float*)(lds + 4096);   // [64][16] sum
    const int fq = kg * 4;
    const int rb = blockIdx.x * 64;

    float mx[4][4];
#pragma unroll
    for (int m = 0; m < 4; ++m)
#pragma unroll
        for (int j = 0; j < 4; ++j) {
            float v = acc[m][0][j];
#pragma unroll
            for (int n = 1; n < 4; ++n) v = fmaxf(v, acc[m][n][j]);
#pragma unroll
            for (int off = 1; off < 16; off <<= 1)
                v = fmaxf(v, __shfl_xor(v, off));
            mx[m][j] = v;
        }
    if (mr == 0) {
#pragma unroll
        for (int m = 0; m < 4; ++m)
#pragma unroll
            for (int j = 0; j < 4; ++j)
                red[(m * 16 + fq + j) * 16 + wid] = mx[m][j];
    }
    __syncthreads();
    if (t < 64) {
        float v = red[t * 16];
#pragma unroll
        for (int w = 1; w < 16; ++w) v = fmaxf(v, red[t * 16 + w]);
        red[t * 16] = v;
    }
    __syncthreads();

    float sm[4][4];
#pragma unroll
    for (int m = 0; m < 4; ++m)
#pragma unroll
        for (int j = 0; j < 4; ++j) {
            float M = red[(m * 16 + fq + j) * 16];
            float s = 0.f;
#pragma unroll
            for (int n = 0; n < 4; ++n) {
                float e = __expf(acc[m][n][j] - M);
                acc[m][n][j] = e;
                s += e;
            }
#pragma unroll
            for (int off = 1; off < 16; off <<= 1)
                s += __shfl_xor(s, off);
            sm[m][j] = s;
        }
    if (mr == 0) {
#pragma unroll
        for (int m = 0; m < 4; ++m)
#pragma unroll
            for (int j = 0; j < 4; ++j)
                red2[(m * 16 + fq + j) * 16 + wid] = sm[m][j];
    }
    __syncthreads();
    if (t < 64) {
        float v = 0.f;
#pragma unroll
        for (int w = 0; w < 16; ++w) v += red2[t * 16 + w];
        red2[t * 16] = 1.0f / v;
    }
    __syncthreads();

#pragma unroll
    for (int m = 0; m < 4; ++m)
#pragma unroll
        for (int j = 0; j < 4; ++j) {
            int grow = rb + m * 16 + fq + j;
            float inv = red2[(m * 16 + fq + j) * 16];
#pragma unroll
            for (int n = 0; n < 4; ++n) {
                int gcol = wid * 64 + n * 16 + mr;
                out[(size_t)grow * 1024 + gcol] = acc[m][n][j] * inv;
            }
        }
}

// ---------------------------------------------------------------------------
extern "C" void kernel_launch(void* const* d_in, const int* in_sizes, int n_in,
                              void* d_out, int out_size, void* d_ws, size_t ws_size,
                              hipStream_t stream) {
    const float* x  = (const float*)d_in[0];
    const float* ft = (const float*)d_in[1];
    const float* lp = (const float*)d_in[2];
    float* out = (float*)d_out;
    char* ws = (char*)d_ws;

    // ws layout: Xh 64Mi | Bpk1 2Mi | BpkL 2Mi | dval 64Mi | Apk 64Mi
    u16* Xh   = (u16*)ws;
    u16* Bpk1 = (u16*)(ws + (size_t)67108864);
    u16* BpkL = Bpk1 + (size_t)NPAD * DIM;
    u16* dval = (u16*)(ws + (size_t)67108864 + 2 * 2097152);
    u16* Apk  = dval + (size_t)BATCH * NPAD;

    prep_x<<<4096, 256, 0, stream>>>((const float4*)x, Xh, BATCH * DIM / 4);
    prep_tp<<<1024, 256, 0, stream>>>(ft, Bpk1);
    prep_lt<<<1024, 256, 0, stream>>>(lp, BpkL);
    gemm1_8p<<<512, 512, 0, stream>>>(Xh, Bpk1, dval);
    probs_kernel<<<8192, 256, 0, stream>>>(dval, Apk);
    gemm2sm<<<512, 1024, 0, stream>>>(Apk, BpkL, out);
}

// Round 12
// 215.700 us; speedup vs baseline: 1.2378x; 1.2378x over previous
//
#include <hip/hip_runtime.h>

// ---------------------------------------------------------------------------
// Soft decision tree forward (all-f16 pipeline), round 12.
//   d = sigmoid(X @ T^T); leaf probs = depth-10 path products;
//   out = softmax(probs @ L)
//
// Round-12: probs pass FUSED into gemm2sm. Each 64-row block expands its own
// leaf probabilities (identical math/index algebra to the r10 probs_kernel)
// directly into LDS in MFMA-fragment-packed layout [kt][m][lane] (128 KB).
// K-loop is the r10-proven barrier-free skeleton: B (BpkL, fragment-packed
// global) direct-to-register with one-step prefetch; A fragments are linear
// conflict-free 1KB ds_read_b128 from LDS. Deletes the probs dispatch and
// 128 MB of Apk traffic, and r10's 16x-redundant A fetch.
// gemm1 reverted to the proven r6 4-phase core (93.6 us). absmax canary:
// arithmetic order unchanged everywhere -> 0.0004882812 exactly.
// ---------------------------------------------------------------------------

typedef unsigned short u16;
typedef unsigned short u16x8 __attribute__((ext_vector_type(8)));
typedef _Float16 f16;
typedef _Float16 f16x8 __attribute__((ext_vector_type(8)));
typedef float f32x4 __attribute__((ext_vector_type(4)));

#define BATCH 32768
#define DIM   1024
#define NPAD  1024

#define WAIT_VM(N) asm volatile("s_waitcnt vmcnt(" #N ")" ::: "memory")
#define BARRIER()  asm volatile("s_barrier" ::: "memory")

// ---- f16 helpers ----
__device__ __forceinline__ u16 f2h(float f) {
    union { f16 h; u16 u; } v; v.h = (f16)f; return v.u;
}
__device__ __forceinline__ float h2f(u16 u) {
    union { u16 u; f16 h; } v; v.u = u; return (float)v.h;
}

// ---- async global->LDS (dest = wave-uniform base + lane*size) ----
__device__ __forceinline__ void gl16(const u16* g, char* l) {
    __builtin_amdgcn_global_load_lds(
        (const __attribute__((address_space(1))) unsigned int*)g,
        (__attribute__((address_space(3))) unsigned int*)l, 16, 0, 0);
}

#define MFMA16(a, b, c) __builtin_amdgcn_mfma_f32_16x16x32_f16(a, b, c, 0, 0, 0)

// ---------------------------------------------------------------------------
// prep: X f32 -> Xh f16 (frozen)
// ---------------------------------------------------------------------------
__global__ __launch_bounds__(256) void prep_x(const float4* __restrict__ x4,
                                              u16* __restrict__ xh, int n4) {
    int stride = gridDim.x * blockDim.x;
    for (int i = blockIdx.x * blockDim.x + threadIdx.x; i < n4; i += stride) {
        float4 v = x4[i];
        *(ushort4*)&xh[(size_t)i * 4] =
            make_ushort4(f2h(v.x), f2h(v.y), f2h(v.z), f2h(v.w));
    }
}

// ---------------------------------------------------------------------------
// prep: thresholds -> Th f16 [1024][1024] linear, row 1023 = 0 (frozen r6)
// ---------------------------------------------------------------------------
__global__ __launch_bounds__(256) void prep_t(const float* __restrict__ t,
                                              u16* __restrict__ th) {
    int i = blockIdx.x * 256 + threadIdx.x;
    int node = i >> 10;
    float v = (node < 1023) ? t[i] : 0.0f;
    th[i] = f2h(v);
}

// ---------------------------------------------------------------------------
// prep: L (1024x1024 f32, [leaf][out]) -> BpkL fragment-packed f16 (frozen)
// BpkL[((b16*32 + kt)*64 + lane)*8 + j] = L[kt*32 + kg*8 + j][b16*16 + mr]
// ---------------------------------------------------------------------------
__global__ __launch_bounds__(256) void prep_lt(const float* __restrict__ L,
                                               u16* __restrict__ BpkL) {
    int o = (blockIdx.x * 256 + threadIdx.x) * 4;
    int b16  = o >> 14;
    int kt   = (o >> 9) & 31;
    int lane = (o >> 3) & 63;
    int j0   = o & 7;
    int mr = lane & 15, kg = lane >> 4;
    int col = b16 * 16 + mr;
    int k0  = kt * 32 + kg * 8 + j0;
    ushort4 v;
    v.x = f2h(L[(size_t)(k0 + 0) * 1024 + col]);
    v.y = f2h(L[(size_t)(k0 + 1) * 1024 + col]);
    v.z = f2h(L[(size_t)(k0 + 2) * 1024 + col]);
    v.w = f2h(L[(size_t)(k0 + 3) * 1024 + col]);
    *(ushort4*)&BpkL[o] = v;
}

// bijective XCD swizzle: 512 blocks, 64 per XCD.
__device__ __forceinline__ void block_map(int bid, int& rb, int& cb) {
    int lid = (bid & 7) * 64 + (bid >> 3);
    rb = (lid >> 2) << 8;
    cb = (lid & 3) << 8;
}

// ---------------------------------------------------------------------------
// GEMM1 core (r6-proven 4-phase 256x256 pipeline, frozen)
// ---------------------------------------------------------------------------
template <int NT>
__device__ __forceinline__ void gemm_core8(const u16* __restrict__ Ap,
                                           const u16* __restrict__ Bp,
                                           int rb, int cb, char* lds,
                                           f32x4 acc[8][4])
{
    const int t = threadIdx.x, wid = t >> 6, lane = t & 63;
    const int wm = wid >> 2, wn = wid & 3;
    const int mr = lane & 15, kg = lane >> 4;

    const int tr = t >> 3;
    const unsigned koff = 8u * ((unsigned)((t & 7) ^ (tr & 7)));
    const unsigned sAlo = (unsigned)(rb + tr) * 1024u + koff;
    const unsigned sAhi = sAlo + 131072u;
    const unsigned sBlo = (unsigned)(cb + tr) * 1024u + koff;
    const unsigned sBhi = sBlo + 131072u;

    const unsigned key = (unsigned)(mr & 7) << 4;
    const unsigned e0 = (unsigned)mr * 128u + (((unsigned)kg * 16u) ^ key);
    const unsigned e1 = (unsigned)mr * 128u + ((64u + (unsigned)kg * 16u) ^ key);
    const unsigned bbase = (unsigned)(wn & 1) * 8192u;
    const unsigned bhalf = (unsigned)(wn >> 1) * 16384u;

#pragma unroll
    for (int m = 0; m < 8; ++m)
#pragma unroll
        for (int n = 0; n < 4; ++n) acc[m][n] = (f32x4){0.f, 0.f, 0.f, 0.f};

    auto stg = [&](int kt, unsigned srcb, const u16* G, int region, int halfo) {
        char* dst = lds + region + (kt & 1) * 32768 + halfo + t * 16;
        const u16* g = G + srcb + (unsigned)kt * 64u;
        gl16(g, dst);
        gl16(g + 65536, dst + 8192);
    };

    stg(0, sAlo, Ap, 0, 0);      stg(0, sAhi, Ap, 0, 16384);
    stg(0, sBlo, Bp, 65536, 0);  stg(0, sBhi, Bp, 65536, 16384);
    stg(1, sAlo, Ap, 0, 0);      stg(1, sAhi, Ap, 0, 16384);
    stg(1, sBlo, Bp, 65536, 0);  stg(1, sBhi, Bp, 65536, 16384);
    WAIT_VM(8);
    BARRIER();

    f16x8 a[4][2], b01[2][2], b23[2][2];

    {
        char* LB = lds + 65536 + bhalf;
#pragma unroll
        for (int n = 0; n < 2; ++n) {
            b01[n][0] = *(const f16x8*)(LB + bbase + n * 2048 + e0);
            b01[n][1] = *(const f16x8*)(LB + bbase + n * 2048 + e1);
        }
    }

#pragma unroll 1
    for (int kt = 0; kt < NT; ++kt) {
        char* LA = lds + (kt & 1) * 32768 + wm * 16384;
        char* LB = lds + 65536 + (kt & 1) * 32768 + bhalf;

        // P1: read a0-3; stage A-lo(t+1); MFMA m0-3 x b01
#pragma unroll
        for (int i = 0; i < 4; ++i) {
            a[i][0] = *(const f16x8*)(LA + i * 2048 + e0);
            a[i][1] = *(const f16x8*)(LA + i * 2048 + e1);
        }
        if (kt + 1 < NT) stg(kt + 1, sAlo, Ap, 0, 0);
        BARRIER();
        __builtin_amdgcn_s_setprio(1);
#pragma unroll
        for (int i = 0; i < 4; ++i)
#pragma unroll
            for (int n = 0; n < 2; ++n) {
                acc[i][n] = MFMA16(a[i][0], b01[n][0], acc[i][n]);
                acc[i][n] = MFMA16(a[i][1], b01[n][1], acc[i][n]);
            }
        __builtin_amdgcn_s_setprio(0);
        BARRIER();

        // P2: read b23; stage A-hi(t+1); MFMA m0-3 x b23
#pragma unroll
        for (int n = 0; n < 2; ++n) {
            b23[n][0] = *(const f16x8*)(LB + bbase + (2 + n) * 2048 + e0);
            b23[n][1] = *(const f16x8*)(LB + bbase + (2 + n) * 2048 + e1);
        }
        if (kt + 1 < NT) stg(kt + 1, sAhi, Ap, 0, 16384);
        BARRIER();
        __builtin_amdgcn_s_setprio(1);
#pragma unroll
        for (int i = 0; i < 4; ++i)
#pragma unroll
            for (int n = 0; n < 2; ++n) {
                acc[i][2 + n] = MFMA16(a[i][0], b23[n][0], acc[i][2 + n]);
                acc[i][2 + n] = MFMA16(a[i][1], b23[n][1], acc[i][2 + n]);
            }
        __builtin_amdgcn_s_setprio(0);
        BARRIER();

        // P3: read a4-7; stage B-lo(t+2); MFMA m4-7 x b23
#pragma unroll
        for (int i = 0; i < 4; ++i) {
            a[i][0] = *(const f16x8*)(LA + (4 + i) * 2048 + e0);
            a[i][1] = *(const f16x8*)(LA + (4 + i) * 2048 + e1);
        }
        if (kt + 2 < NT) stg(kt + 2, sBlo, Bp, 65536, 0);
        BARRIER();
        __builtin_amdgcn_s_setprio(1);
#pragma unroll
        for (int i = 0; i < 4; ++i)
#pragma unroll
            for (int n = 0; n < 2; ++n) {
                acc[4 + i][2 + n] = MFMA16(a[i][0], b23[n][0], acc[4 + i][2 + n]);
                acc[4 + i][2 + n] = MFMA16(a[i][1], b23[n][1], acc[4 + i][2 + n]);
            }
        __builtin_amdgcn_s_setprio(0);
        BARRIER();

        // P4: stage B-hi(t+2); MFMA m4-7 x b01; gates; read b01(t+1)
        if (kt + 2 < NT) stg(kt + 2, sBhi, Bp, 65536, 16384);
        BARRIER();
        __builtin_amdgcn_s_setprio(1);
#pragma unroll
        for (int i = 0; i < 4; ++i)
#pragma unroll
            for (int n = 0; n < 2; ++n) {
                acc[4 + i][n] = MFMA16(a[i][0], b01[n][0], acc[4 + i][n]);
                acc[4 + i][n] = MFMA16(a[i][1], b01[n][1], acc[4 + i][n]);
            }
        __builtin_amdgcn_s_setprio(0);
        if (kt + 1 < NT) {
            if (kt + 2 < NT) { WAIT_VM(8); } else { WAIT_VM(4); }
            char* LB2 = lds + 65536 + ((kt + 1) & 1) * 32768 + bhalf;
#pragma unroll
            for (int n = 0; n < 2; ++n) {
                b01[n][0] = *(const f16x8*)(LB2 + bbase + n * 2048 + e0);
                b01[n][1] = *(const f16x8*)(LB2 + bbase + n * 2048 + e1);
            }
            if (kt + 2 < NT) { WAIT_VM(4); } else { WAIT_VM(0); }
        }
        BARRIER();
    }
}

// ---------------------------------------------------------------------------
// GEMM1: d = sigmoid(X @ T^T), store d f16 (frozen r6)
// ---------------------------------------------------------------------------
__global__ __launch_bounds__(512, 2) void gemm1_8p(
    const u16* __restrict__ Xh, const u16* __restrict__ Th,
    u16* __restrict__ dval)
{
    __shared__ __align__(16) char lds[131072];
    int rb, cb;
    block_map(blockIdx.x, rb, cb);
    f32x4 acc[8][4];
    gemm_core8<16>(Xh, Th, rb, cb, lds, acc);

    const int lane = threadIdx.x & 63, wid = threadIdx.x >> 6;
    const int wm = wid >> 2, wn = wid & 3;
    const int mr = lane & 15, fq = (lane >> 4) * 4;
#pragma unroll
    for (int m = 0; m < 8; ++m)
#pragma unroll
        for (int j = 0; j < 4; ++j) {
            int grow = rb + wm * 128 + m * 16 + fq + j;
#pragma unroll
            for (int n = 0; n < 4; ++n) {
                int gcol = cb + wn * 64 + n * 16 + mr;
                float s = acc[m][n][j];
                float d = 1.0f / (1.0f + __expf(-s));
                dval[(size_t)grow * NPAD + gcol] = f2h(d);
            }
        }
}

// ---------------------------------------------------------------------------
// FUSED TREE-EXPANSION + GEMM2 + SOFTMAX, round 12.
// Block = 64 full rows, 1024 threads / 16 waves; wave wid owns cols wid*64:
// acc[4][4].
// Phase 1: each wave expands 4 rows (lrow = wid*4+r) from dval (global,
//   L2/L3-served, same access pattern as the retired probs_kernel) and
//   writes fragment-packed probs to LDS: byte (kt*4+m)*1024 + lane'*16 + j*2.
// Phase 2: barrier-free K-loop (r10 skeleton): B direct-reg 1-step-prefetch
//   dbuf; A = linear conflict-free ds_read_b128 from LDS.
// Phase 3: in-register softmax (red arrays reuse dead frag space).
// ---------------------------------------------------------------------------
__global__ __launch_bounds__(1024, 1) void gemm2sm(
    const u16* __restrict__ dval, const u16* __restrict__ BpkL,
    float* __restrict__ out)
{
    __shared__ __align__(16) char lds[131072];
    const int t = threadIdx.x, wid = t >> 6, lane = t & 63;
    const int mr = lane & 15, kg = lane >> 4;
    const int rb = blockIdx.x * 64;

    // ---------------- phase 1: tree expansion -> LDS packed ----------------
#pragma unroll 1
    for (int r = 0; r < 4; ++r) {
        const int lrow = wid * 4 + r;
        const u16* dp = dval + (size_t)(rb + lrow) * NPAD;
        const int l = lane;

        float prod = 1.0f;
#pragma unroll
        for (int lev = 0; lev < 6; lev++) {
            int node = (1 << lev) - 1 + (l >> (6 - lev));
            int bit  = (l >> (5 - lev)) & 1;
            float v = h2f(dp[node]);
            prod *= bit ? (1.0f - v) : v;
        }
        float d6 = h2f(dp[63 + l]);
        float d7[2], d8[4], d9[8];
#pragma unroll
        for (int j = 0; j < 2; j++) d7[j] = h2f(dp[127 + 2 * l + j]);
#pragma unroll
        for (int j = 0; j < 4; j++) d8[j] = h2f(dp[255 + 4 * l + j]);
#pragma unroll
        for (int j = 0; j < 8; j++) d9[j] = h2f(dp[511 + 8 * l + j]);

        u16 outv[16];
#pragma unroll
        for (int j = 0; j < 16; j++) {
            float f6 = (j >> 3) ? (1.0f - d6) : d6;
            float v7 = d7[j >> 3];  float f7 = ((j >> 2) & 1) ? (1.0f - v7) : v7;
            float v8 = d8[j >> 2];  float f8 = ((j >> 1) & 1) ? (1.0f - v8) : v8;
            float v9 = d9[j >> 1];  float f9 = (j & 1) ? (1.0f - v9) : v9;
            outv[j] = f2h(prod * f6 * f7 * f8 * f9);
        }

        // packed LDS write: kt = l>>1, kg0 = (l&1)*2 (+1 for second chunk)
        const int m = lrow >> 4, mrr = lrow & 15;
        const int kg0 = (l & 1) * 2;
        char* base = lds + (((l >> 1) * 4 + m) << 10);
        *(u16x8*)(base + (kg0 * 16 + mrr) * 16) =
            (u16x8){outv[0], outv[1], outv[2], outv[3],
                    outv[4], outv[5], outv[6], outv[7]};
        *(u16x8*)(base + ((kg0 + 1) * 16 + mrr) * 16) =
            (u16x8){outv[8], outv[9], outv[10], outv[11],
                    outv[12], outv[13], outv[14], outv[15]};
    }
    __syncthreads();

    // ---------------- phase 2: barrier-free K-loop ----------------
    const u16* bbase = BpkL + (size_t)(wid * 4) * 16384 + (unsigned)lane * 8u;
    const unsigned aoff = (unsigned)lane * 16u;

    f32x4 acc[4][4];
#pragma unroll
    for (int m = 0; m < 4; ++m)
#pragma unroll
        for (int n = 0; n < 4; ++n) acc[m][n] = (f32x4){0.f, 0.f, 0.f, 0.f};

    f16x8 bA[4], bB[4];
#pragma unroll
    for (int n = 0; n < 4; ++n) bA[n] = *(const f16x8*)(bbase + n * 16384);

    auto step = [&](int kt, f16x8 (&bu)[4], f16x8 (&bl)[4]) {
        if (kt + 1 < 32) {
#pragma unroll
            for (int n = 0; n < 4; ++n)
                bl[n] = *(const f16x8*)(bbase + n * 16384 + (unsigned)(kt + 1) * 512u);
        }
        f16x8 a[4];
#pragma unroll
        for (int m = 0; m < 4; ++m)
            a[m] = *(const f16x8*)(lds + (((kt << 2) + m) << 10) + aoff);
        __builtin_amdgcn_s_setprio(1);
#pragma unroll
        for (int m = 0; m < 4; ++m)
#pragma unroll
            for (int n = 0; n < 4; ++n)
                acc[m][n] = MFMA16(a[m], bu[n], acc[m][n]);
        __builtin_amdgcn_s_setprio(0);
    };

#pragma unroll 1
    for (int k2 = 0; k2 < 16; ++k2) {
        step(2 * k2, bA, bB);
        step(2 * k2 + 1, bB, bA);
    }

    __syncthreads();   // all waves done with LDS frags before red reuse

    // ---------------- phase 3: in-register softmax ----------------
    // thread rows: r(m,j) = m*16 + kg*4 + j; cols: wid*64 + n*16 + mr
    float* red  = (float*)lds;            // [64][16] max
    float* red2 = (float*)(lds + 4096);   // [64][16] sum
    const int fq = kg * 4;

    float mx[4][4];
#pragma unroll
    for (int m = 0; m < 4; ++m)
#pragma unroll
        for (int j = 0; j < 4; ++j) {
            float v = acc[m][0][j];
#pragma unroll
            for (int n = 1; n < 4; ++n) v = fmaxf(v, acc[m][n][j]);
#pragma unroll
            for (int off = 1; off < 16; off <<= 1)
                v = fmaxf(v, __shfl_xor(v, off));
            mx[m][j] = v;
        }
    if (mr == 0) {
#pragma unroll
        for (int m = 0; m < 4; ++m)
#pragma unroll
            for (int j = 0; j < 4; ++j)
                red[(m * 16 + fq + j) * 16 + wid] = mx[m][j];
    }
    __syncthreads();
    if (t < 64) {
        float v = red[t * 16];
#pragma unroll
        for (int w = 1; w < 16; ++w) v = fmaxf(v, red[t * 16 + w]);
        red[t * 16] = v;
    }
    __syncthreads();

    float sm[4][4];
#pragma unroll
    for (int m = 0; m < 4; ++m)
#pragma unroll
        for (int j = 0; j < 4; ++j) {
            float M = red[(m * 16 + fq + j) * 16];
            float s = 0.f;
#pragma unroll
            for (int n = 0; n < 4; ++n) {
                float e = __expf(acc[m][n][j] - M);
                acc[m][n][j] = e;
                s += e;
            }
#pragma unroll
            for (int off = 1; off < 16; off <<= 1)
                s += __shfl_xor(s, off);
            sm[m][j] = s;
        }
    if (mr == 0) {
#pragma unroll
        for (int m = 0; m < 4; ++m)
#pragma unroll
            for (int j = 0; j < 4; ++j)
                red2[(m * 16 + fq + j) * 16 + wid] = sm[m][j];
    }
    __syncthreads();
    if (t < 64) {
        float v = 0.f;
#pragma unroll
        for (int w = 0; w < 16; ++w) v += red2[t * 16 + w];
        red2[t * 16] = 1.0f / v;
    }
    __syncthreads();

#pragma unroll
    for (int m = 0; m < 4; ++m)
#pragma unroll
        for (int j = 0; j < 4; ++j) {
            int grow = rb + m * 16 + fq + j;
            float inv = red2[(m * 16 + fq + j) * 16];
#pragma unroll
            for (int n = 0; n < 4; ++n) {
                int gcol = wid * 64 + n * 16 + mr;
                out[(size_t)grow * 1024 + gcol] = acc[m][n][j] * inv;
            }
        }
}

// ---------------------------------------------------------------------------
extern "C" void kernel_launch(void* const* d_in, const int* in_sizes, int n_in,
                              void* d_out, int out_size, void* d_ws, size_t ws_size,
                              hipStream_t stream) {
    const float* x  = (const float*)d_in[0];
    const float* ft = (const float*)d_in[1];
    const float* lp = (const float*)d_in[2];
    float* out = (float*)d_out;
    char* ws = (char*)d_ws;

    // ws layout: Xh 64Mi | Th 2Mi | BpkL 2Mi | dval 64Mi
    u16* Xh   = (u16*)ws;
    u16* Th   = (u16*)(ws + (size_t)67108864);
    u16* BpkL = Th + (size_t)NPAD * DIM;
    u16* dval = (u16*)(ws + (size_t)67108864 + 2 * 2097152);

    prep_x<<<4096, 256, 0, stream>>>((const float4*)x, Xh, BATCH * DIM / 4);
    prep_t<<<4096, 256, 0, stream>>>(ft, Th);
    prep_lt<<<1024, 256, 0, stream>>>(lp, BpkL);
    gemm1_8p<<<512, 512, 0, stream>>>(Xh, Th, dval);
    gemm2sm<<<512, 1024, 0, stream>>>(dval, BpkL, out);
}

// Round 13
// 212.867 us; speedup vs baseline: 1.2542x; 1.0133x over previous
//
#include <hip/hip_runtime.h>

// ---------------------------------------------------------------------------
// Soft decision tree forward (all-f16), round 13: ONE mega-kernel.
//   d = sigmoid(X @ T^T); leaf probs = depth-10 path products;
//   out = softmax(probs @ L)
//
// Each 64-row block (1024 thr / 16 waves; wave wid owns cols wid*64):
//   A) stage Xh rows (128 KB) -> LDS once (k-XOR swizzled rows);
//   B) gemm1: barrier-free K-loop (A ds_read, B=Bpk1 packed direct-reg dbuf);
//   C) sigmoid -> d redistributed via LDS [64][2048B] (overwrites Xh);
//   D) tree expansion (r12 math) from d-LDS; probs held in regs across a
//      barrier, then written fragment-packed with slot-XOR (kt&7) (8-way
//      instead of r12's 32-way write conflict);
//   E) gemm2: barrier-free K-loop (A ds_read w/ slot-XOR, B=BpkL direct-reg);
//   F) in-register softmax, final f32 write.
// Deletes: gemm1_8p dispatch, dval 128MB round-trip, prep_t.
// Canary: all per-output MFMA accumulation sequences unchanged ->
// absmax must be exactly 0.0004882812.
// ---------------------------------------------------------------------------

typedef unsigned short u16;
typedef unsigned short u16x8 __attribute__((ext_vector_type(8)));
typedef _Float16 f16;
typedef _Float16 f16x8 __attribute__((ext_vector_type(8)));
typedef float f32x4 __attribute__((ext_vector_type(4)));

#define BATCH 32768
#define DIM   1024
#define NPAD  1024

#define WAIT_VM(N) asm volatile("s_waitcnt vmcnt(" #N ")" ::: "memory")
#define BARRIER()  asm volatile("s_barrier" ::: "memory")

// ---- f16 helpers ----
__device__ __forceinline__ u16 f2h(float f) {
    union { f16 h; u16 u; } v; v.h = (f16)f; return v.u;
}
__device__ __forceinline__ float h2f(u16 u) {
    union { u16 u; f16 h; } v; v.u = u; return (float)v.h;
}

// ---- async global->LDS (dest = wave-uniform base + lane*size) ----
__device__ __forceinline__ void gl16(const u16* g, char* l) {
    __builtin_amdgcn_global_load_lds(
        (const __attribute__((address_space(1))) unsigned int*)g,
        (__attribute__((address_space(3))) unsigned int*)l, 16, 0, 0);
}

#define MFMA16(a, b, c) __builtin_amdgcn_mfma_f32_16x16x32_f16(a, b, c, 0, 0, 0)

// ---------------------------------------------------------------------------
// prep: X f32 -> Xh f16 row-major (frozen)
// ---------------------------------------------------------------------------
__global__ __launch_bounds__(256) void prep_x(const float4* __restrict__ x4,
                                              u16* __restrict__ xh, int n4) {
    int stride = gridDim.x * blockDim.x;
    for (int i = blockIdx.x * blockDim.x + threadIdx.x; i < n4; i += stride) {
        float4 v = x4[i];
        *(ushort4*)&xh[(size_t)i * 4] =
            make_ushort4(f2h(v.x), f2h(v.y), f2h(v.z), f2h(v.w));
    }
}

// ---------------------------------------------------------------------------
// prep: thresholds -> Bpk1 fragment-packed f16 (node row 1023 = 0; r11-proven)
// Bpk1[((n16*32 + kt)*64 + lane)*8 + j] = T[n16*16 + mr][kt*32 + kg*8 + j]
// ---------------------------------------------------------------------------
__global__ __launch_bounds__(256) void prep_tp(const float* __restrict__ t,
                                               u16* __restrict__ Bpk1) {
    int o = (blockIdx.x * 256 + threadIdx.x) * 4;
    int n16  = o >> 14;
    int kt   = (o >> 9) & 31;
    int lane = (o >> 3) & 63;
    int j0   = o & 7;
    int mr = lane & 15, kg = lane >> 4;
    int node = n16 * 16 + mr;
    int k0  = kt * 32 + kg * 8 + j0;
    ushort4 v = make_ushort4(0, 0, 0, 0);
    if (node < 1023) {
        const float* src = t + (size_t)node * 1024 + k0;
        v.x = f2h(src[0]); v.y = f2h(src[1]);
        v.z = f2h(src[2]); v.w = f2h(src[3]);
    }
    *(ushort4*)&Bpk1[o] = v;
}

// ---------------------------------------------------------------------------
// prep: L (1024x1024 f32, [leaf][out]) -> BpkL fragment-packed f16 (frozen)
// ---------------------------------------------------------------------------
__global__ __launch_bounds__(256) void prep_lt(const float* __restrict__ L,
                                               u16* __restrict__ BpkL) {
    int o = (blockIdx.x * 256 + threadIdx.x) * 4;
    int b16  = o >> 14;
    int kt   = (o >> 9) & 31;
    int lane = (o >> 3) & 63;
    int j0   = o & 7;
    int mr = lane & 15, kg = lane >> 4;
    int col = b16 * 16 + mr;
    int k0  = kt * 32 + kg * 8 + j0;
    ushort4 v;
    v.x = f2h(L[(size_t)(k0 + 0) * 1024 + col]);
    v.y = f2h(L[(size_t)(k0 + 1) * 1024 + col]);
    v.z = f2h(L[(size_t)(k0 + 2) * 1024 + col]);
    v.w = f2h(L[(size_t)(k0 + 3) * 1024 + col]);
    *(ushort4*)&BpkL[o] = v;
}

// ---------------------------------------------------------------------------
// MEGA KERNEL
// ---------------------------------------------------------------------------
__global__ __launch_bounds__(1024, 1) void megak(
    const u16* __restrict__ Xh, const u16* __restrict__ Bpk1,
    const u16* __restrict__ BpkL, float* __restrict__ out)
{
    __shared__ __align__(16) char lds[131072];
    const int t = threadIdx.x, wid = t >> 6, lane = t & 63;
    const int mr = lane & 15, kg = lane >> 4;
    const int rb = blockIdx.x * 64;
    const int fq = kg * 4;

    // ---------------- phase A: stage Xh block -> LDS (once) ----------------
    // LDS rows [64][2048B]; within-row bytes store source k-byte
    // (woff ^ ((row&7)<<4)).  dest = wave-uniform + lane*16.
    {
        const unsigned woff = (unsigned)((wid & 1) * 1024 + lane * 16);
        const int rowbase = wid >> 1;
#pragma unroll
        for (int c = 0; c < 8; ++c) {
            int row = c * 8 + rowbase;
            unsigned key = (unsigned)(row & 7) << 4;
            const u16* src = Xh + (size_t)(rb + row) * 1024 + ((woff ^ key) >> 1);
            gl16(src, lds + c * 16384 + t * 16);
        }
    }

    // b1(0) prefetch (stays in flight across the gate)
    const u16* bbase1[4];
#pragma unroll
    for (int n = 0; n < 4; ++n)
        bbase1[n] = Bpk1 + (size_t)(wid * 4 + n) * 16384 + (unsigned)lane * 8u;

    f16x8 bA[4], bB[4];
#pragma unroll
    for (int n = 0; n < 4; ++n) bA[n] = *(const f16x8*)(bbase1[n]);

    WAIT_VM(4);     // 8 stage-loads done; bA still in flight
    BARRIER();

    // ---------------- phase B: gemm1 barrier-free K-loop ----------------
    const unsigned keyA1 = (unsigned)(mr & 7) << 4;
    unsigned offA1[4];
#pragma unroll
    for (int m = 0; m < 4; ++m) offA1[m] = (unsigned)((m * 16 + mr) * 2048);

    f32x4 acc[4][4];
#pragma unroll
    for (int m = 0; m < 4; ++m)
#pragma unroll
        for (int n = 0; n < 4; ++n) acc[m][n] = (f32x4){0.f, 0.f, 0.f, 0.f};

    auto step1 = [&](int kt, f16x8 (&bu)[4], f16x8 (&bl)[4]) {
        if (kt + 1 < 32) {
#pragma unroll
            for (int n = 0; n < 4; ++n)
                bl[n] = *(const f16x8*)(bbase1[n] + (unsigned)(kt + 1) * 512u);
        }
        const unsigned ko = ((unsigned)(kt * 64) + (unsigned)kg * 16u) ^ keyA1;
        f16x8 a[4];
#pragma unroll
        for (int m = 0; m < 4; ++m)
            a[m] = *(const f16x8*)(lds + offA1[m] + ko);
        __builtin_amdgcn_s_setprio(1);
#pragma unroll
        for (int m = 0; m < 4; ++m)
#pragma unroll
            for (int n = 0; n < 4; ++n)
                acc[m][n] = MFMA16(a[m], bu[n], acc[m][n]);
        __builtin_amdgcn_s_setprio(0);
    };

#pragma unroll 1
    for (int k2 = 0; k2 < 16; ++k2) {
        step1(2 * k2, bA, bB);
        step1(2 * k2 + 1, bB, bA);
    }

    // ---------------- phase C: sigmoid -> d into LDS [64][2048B] ----------
    __syncthreads();     // all waves done reading Xh-LDS
#pragma unroll
    for (int m = 0; m < 4; ++m)
#pragma unroll
        for (int j = 0; j < 4; ++j) {
            int row = m * 16 + fq + j;
#pragma unroll
            for (int n = 0; n < 4; ++n) {
                int col = wid * 64 + n * 16 + mr;
                float s = acc[m][n][j];
                float dv = 1.0f / (1.0f + __expf(-s));
                *(u16*)(lds + row * 2048 + col * 2) = f2h(dv);
            }
        }
    __syncthreads();     // d complete

    // ---------------- phase D: tree expansion (r12 math, d from LDS) ------
    u16x8 pk[4][2];
#pragma unroll
    for (int r = 0; r < 4; ++r) {
        const int lrow = wid * 4 + r;
        const u16* dp = (const u16*)(lds + lrow * 2048);
        const int l = lane;

        float prod = 1.0f;
#pragma unroll
        for (int lev = 0; lev < 6; lev++) {
            int node = (1 << lev) - 1 + (l >> (6 - lev));
            int bit  = (l >> (5 - lev)) & 1;
            float v = h2f(dp[node]);
            prod *= bit ? (1.0f - v) : v;
        }
        float d6 = h2f(dp[63 + l]);
        float d7[2], d8[4], d9[8];
#pragma unroll
        for (int j = 0; j < 2; j++) d7[j] = h2f(dp[127 + 2 * l + j]);
#pragma unroll
        for (int j = 0; j < 4; j++) d8[j] = h2f(dp[255 + 4 * l + j]);
#pragma unroll
        for (int j = 0; j < 8; j++) d9[j] = h2f(dp[511 + 8 * l + j]);

        u16 outv[16];
#pragma unroll
        for (int j = 0; j < 16; j++) {
            float f6 = (j >> 3) ? (1.0f - d6) : d6;
            float v7 = d7[j >> 3];  float f7 = ((j >> 2) & 1) ? (1.0f - v7) : v7;
            float v8 = d8[j >> 2];  float f8 = ((j >> 1) & 1) ? (1.0f - v8) : v8;
            float v9 = d9[j >> 1];  float f9 = (j & 1) ? (1.0f - v9) : v9;
            outv[j] = f2h(prod * f6 * f7 * f8 * f9);
        }
        pk[r][0] = (u16x8){outv[0], outv[1], outv[2], outv[3],
                           outv[4], outv[5], outv[6], outv[7]};
        pk[r][1] = (u16x8){outv[8], outv[9], outv[10], outv[11],
                           outv[12], outv[13], outv[14], outv[15]};
    }
    __syncthreads();     // all d reads done before probs overwrite

    // packed probs write, slot-XOR (kt&7): 8-way instead of 32-way conflicts
    {
        const int ktw = lane >> 1, kg0 = (lane & 1) * 2;
        const unsigned K = (unsigned)(ktw & 7);
#pragma unroll
        for (int r = 0; r < 4; ++r) {
            const int lrow = wid * 4 + r;
            const int m = lrow >> 4, mrr = lrow & 15;
            char* base = lds + (((ktw << 2) + m) << 10);
            unsigned s0 = ((unsigned)(kg0 * 16 + mrr)) ^ K;
            unsigned s1 = ((unsigned)((kg0 + 1) * 16 + mrr)) ^ K;
            *(u16x8*)(base + s0 * 16) = pk[r][0];
            *(u16x8*)(base + s1 * 16) = pk[r][1];
        }
    }
    __syncthreads();     // probs complete

    // ---------------- phase E: gemm2 barrier-free K-loop ----------------
    const u16* bbase2 = BpkL + (size_t)(wid * 4) * 16384 + (unsigned)lane * 8u;

#pragma unroll
    for (int m = 0; m < 4; ++m)
#pragma unroll
        for (int n = 0; n < 4; ++n) acc[m][n] = (f32x4){0.f, 0.f, 0.f, 0.f};

#pragma unroll
    for (int n = 0; n < 4; ++n) bA[n] = *(const f16x8*)(bbase2 + n * 16384);

    auto step2 = [&](int kt, f16x8 (&bu)[4], f16x8 (&bl)[4]) {
        if (kt + 1 < 32) {
#pragma unroll
            for (int n = 0; n < 4; ++n)
                bl[n] = *(const f16x8*)(bbase2 + n * 16384 + (unsigned)(kt + 1) * 512u);
        }
        const unsigned sl = ((unsigned)(lane ^ (kt & 7))) << 4;
        f16x8 a[4];
#pragma unroll
        for (int m = 0; m < 4; ++m)
            a[m] = *(const f16x8*)(lds + (((kt << 2) + m) << 10) + sl);
        __builtin_amdgcn_s_setprio(1);
#pragma unroll
        for (int m = 0; m < 4; ++m)
#pragma unroll
            for (int n = 0; n < 4; ++n)
                acc[m][n] = MFMA16(a[m], bu[n], acc[m][n]);
        __builtin_amdgcn_s_setprio(0);
    };

#pragma unroll 1
    for (int k2 = 0; k2 < 16; ++k2) {
        step2(2 * k2, bA, bB);
        step2(2 * k2 + 1, bB, bA);
    }

    __syncthreads();     // all probs reads done before red reuse

    // ---------------- phase F: in-register softmax (r12 verbatim) ---------
    float* red  = (float*)lds;            // [64][16] max
    float* red2 = (float*)(lds + 4096);   // [64][16] sum

    float mx[4][4];
#pragma unroll
    for (int m = 0; m < 4; ++m)
#pragma unroll
        for (int j = 0; j < 4; ++j) {
            float v = acc[m][0][j];
#pragma unroll
            for (int n = 1; n < 4; ++n) v = fmaxf(v, acc[m][n][j]);
#pragma unroll
            for (int off = 1; off < 16; off <<= 1)
                v = fmaxf(v, __shfl_xor(v, off));
            mx[m][j] = v;
        }
    if (mr == 0) {
#pragma unroll
        for (int m = 0; m < 4; ++m)
#pragma unroll
            for (int j = 0; j < 4; ++j)
                red[(m * 16 + fq + j) * 16 + wid] = mx[m][j];
    }
    __syncthreads();
    if (t < 64) {
        float v = red[t * 16];
#pragma unroll
        for (int w = 1; w < 16; ++w) v = fmaxf(v, red[t * 16 + w]);
        red[t * 16] = v;
    }
    __syncthreads();

    float sm[4][4];
#pragma unroll
    for (int m = 0; m < 4; ++m)
#pragma unroll
        for (int j = 0; j < 4; ++j) {
            float M = red[(m * 16 + fq + j) * 16];
            float s = 0.f;
#pragma unroll
            for (int n = 0; n < 4; ++n) {
                float e = __expf(acc[m][n][j] - M);
                acc[m][n][j] = e;
                s += e;
            }
#pragma unroll
            for (int off = 1; off < 16; off <<= 1)
                s += __shfl_xor(s, off);
            sm[m][j] = s;
        }
    if (mr == 0) {
#pragma unroll
        for (int m = 0; m < 4; ++m)
#pragma unroll
            for (int j = 0; j < 4; ++j)
                red2[(m * 16 + fq + j) * 16 + wid] = sm[m][j];
    }
    __syncthreads();
    if (t < 64) {
        float v = 0.f;
#pragma unroll
        for (int w = 0; w < 16; ++w) v += red2[t * 16 + w];
        red2[t * 16] = 1.0f / v;
    }
    __syncthreads();

#pragma unroll
    for (int m = 0; m < 4; ++m)
#pragma unroll
        for (int j = 0; j < 4; ++j) {
            int grow = rb + m * 16 + fq + j;
            float inv = red2[(m * 16 + fq + j) * 16];
#pragma unroll
            for (int n = 0; n < 4; ++n) {
                int gcol = wid * 64 + n * 16 + mr;
                out[(size_t)grow * 1024 + gcol] = acc[m][n][j] * inv;
            }
        }
}

// ---------------------------------------------------------------------------
extern "C" void kernel_launch(void* const* d_in, const int* in_sizes, int n_in,
                              void* d_out, int out_size, void* d_ws, size_t ws_size,
                              hipStream_t stream) {
    const float* x  = (const float*)d_in[0];
    const float* ft = (const float*)d_in[1];
    const float* lp = (const float*)d_in[2];
    float* out = (float*)d_out;
    char* ws = (char*)d_ws;

    // ws layout: Xh 64Mi | Bpk1 2Mi | BpkL 2Mi
    u16* Xh   = (u16*)ws;
    u16* Bpk1 = (u16*)(ws + (size_t)67108864);
    u16* BpkL = Bpk1 + (size_t)NPAD * DIM;

    prep_x<<<4096, 256, 0, stream>>>((const float4*)x, Xh, BATCH * DIM / 4);
    prep_tp<<<1024, 256, 0, stream>>>(ft, Bpk1);
    prep_lt<<<1024, 256, 0, stream>>>(lp, BpkL);
    megak<<<512, 1024, 0, stream>>>(Xh, Bpk1, BpkL, out);
}

// Round 14
// 183.958 us; speedup vs baseline: 1.4513x; 1.1571x over previous
//
#include <hip/hip_runtime.h>

// ---------------------------------------------------------------------------
// Soft decision tree forward (all-f16), round 14: mega-kernel + fused X
// conversion + conflict-free d layout.
//   d = sigmoid(X @ T^T); leaf probs = depth-10 path products;
//   out = softmax(probs @ L)
//
// vs round 13 (structure frozen):
//  - prep_x DELETED: megak phase A loads X f32 directly (coalesced float4
//    pairs at the same XOR-swizzled addresses), converts with the identical
//    f2h, writes the identical LDS layout via ds_write_b128. Saves the
//    dispatch + 128 MB Xh round-trip.
//  - d layout: stride 2112 B/row, node base +2 (16B-aligns lev-9 groups),
//    XOR key ((row>>2)&3)<<4 = kg-distinct. Phase-C writes 8-way -> ~2-way
//    conflicts; phase-D reads become b128/b64/b32 vectors.
// Canary: all arithmetic unchanged -> absmax exactly 0.0004882812.
// ---------------------------------------------------------------------------

typedef unsigned short u16;
typedef unsigned short u16x8 __attribute__((ext_vector_type(8)));
typedef _Float16 f16;
typedef _Float16 f16x8 __attribute__((ext_vector_type(8)));
typedef float f32x4 __attribute__((ext_vector_type(4)));

#define BATCH 32768
#define DIM   1024
#define NPAD  1024
#define DSTRIDE 2112

#define WAIT_VM(N) asm volatile("s_waitcnt vmcnt(" #N ")" ::: "memory")
#define BARRIER()  asm volatile("s_barrier" ::: "memory")

// ---- f16 helpers ----
__device__ __forceinline__ u16 f2h(float f) {
    union { f16 h; u16 u; } v; v.h = (f16)f; return v.u;
}
__device__ __forceinline__ float h2f(u16 u) {
    union { u16 u; f16 h; } v; v.u = u; return (float)v.h;
}

#define MFMA16(a, b, c) __builtin_amdgcn_mfma_f32_16x16x32_f16(a, b, c, 0, 0, 0)

// ---------------------------------------------------------------------------
// prep: thresholds -> Bpk1 fragment-packed f16 (node row 1023 = 0; r11-proven)
// Bpk1[((n16*32 + kt)*64 + lane)*8 + j] = T[n16*16 + mr][kt*32 + kg*8 + j]
// ---------------------------------------------------------------------------
__global__ __launch_bounds__(256) void prep_tp(const float* __restrict__ t,
                                               u16* __restrict__ Bpk1) {
    int o = (blockIdx.x * 256 + threadIdx.x) * 4;
    int n16  = o >> 14;
    int kt   = (o >> 9) & 31;
    int lane = (o >> 3) & 63;
    int j0   = o & 7;
    int mr = lane & 15, kg = lane >> 4;
    int node = n16 * 16 + mr;
    int k0  = kt * 32 + kg * 8 + j0;
    ushort4 v = make_ushort4(0, 0, 0, 0);
    if (node < 1023) {
        const float* src = t + (size_t)node * 1024 + k0;
        v.x = f2h(src[0]); v.y = f2h(src[1]);
        v.z = f2h(src[2]); v.w = f2h(src[3]);
    }
    *(ushort4*)&Bpk1[o] = v;
}

// ---------------------------------------------------------------------------
// prep: L (1024x1024 f32, [leaf][out]) -> BpkL fragment-packed f16 (frozen)
// ---------------------------------------------------------------------------
__global__ __launch_bounds__(256) void prep_lt(const float* __restrict__ L,
                                               u16* __restrict__ BpkL) {
    int o = (blockIdx.x * 256 + threadIdx.x) * 4;
    int b16  = o >> 14;
    int kt   = (o >> 9) & 31;
    int lane = (o >> 3) & 63;
    int j0   = o & 7;
    int mr = lane & 15, kg = lane >> 4;
    int col = b16 * 16 + mr;
    int k0  = kt * 32 + kg * 8 + j0;
    ushort4 v;
    v.x = f2h(L[(size_t)(k0 + 0) * 1024 + col]);
    v.y = f2h(L[(size_t)(k0 + 1) * 1024 + col]);
    v.z = f2h(L[(size_t)(k0 + 2) * 1024 + col]);
    v.w = f2h(L[(size_t)(k0 + 3) * 1024 + col]);
    *(ushort4*)&BpkL[o] = v;
}

// ---------------------------------------------------------------------------
// MEGA KERNEL
// ---------------------------------------------------------------------------
__global__ __launch_bounds__(1024, 1) void megak(
    const float* __restrict__ X, const u16* __restrict__ Bpk1,
    const u16* __restrict__ BpkL, float* __restrict__ out)
{
    __shared__ __align__(16) char lds[135168];
    const int t = threadIdx.x, wid = t >> 6, lane = t & 63;
    const int mr = lane & 15, kg = lane >> 4;
    const int rb = blockIdx.x * 64;
    const int fq = kg * 4;

    const u16* bbase1[4];
#pragma unroll
    for (int n = 0; n < 4; ++n)
        bbase1[n] = Bpk1 + (size_t)(wid * 4 + n) * 16384 + (unsigned)lane * 8u;

    f16x8 bA[4], bB[4];

    // ---------------- phase A: X f32 -> f16 LDS [64][2048B] ----------------
    // Same layout/addressing as r13 gl16 path: row byte w holds global
    // f16-k-byte (w ^ ((row&7)<<4)); dest chunk = lds + c*16384 + t*16.
    {
        const unsigned woff = (unsigned)((wid & 1) * 1024 + lane * 16);
        const int rowbase = wid >> 1;
        float4 xlo[8], xhi[8];
#pragma unroll
        for (int c = 0; c < 8; ++c) {
            int row = c * 8 + rowbase;
            unsigned key = (unsigned)(row & 7) << 4;
            const float* src = X + (size_t)(rb + row) * 1024 + ((woff ^ key) >> 1);
            xlo[c] = *(const float4*)src;
            xhi[c] = *(const float4*)(src + 4);
        }
        // b1(0) issued AFTER X loads (youngest) -> stays in flight
#pragma unroll
        for (int n = 0; n < 4; ++n) bA[n] = *(const f16x8*)(bbase1[n]);
#pragma unroll
        for (int c = 0; c < 8; ++c) {
            u16x8 h;
            h[0] = f2h(xlo[c].x); h[1] = f2h(xlo[c].y);
            h[2] = f2h(xlo[c].z); h[3] = f2h(xlo[c].w);
            h[4] = f2h(xhi[c].x); h[5] = f2h(xhi[c].y);
            h[6] = f2h(xhi[c].z); h[7] = f2h(xhi[c].w);
            *(u16x8*)(lds + c * 16384 + t * 16) = h;
        }
    }
    asm volatile("s_waitcnt lgkmcnt(0)" ::: "memory");
    BARRIER();

    // ---------------- phase B: gemm1 barrier-free K-loop ----------------
    const unsigned keyA1 = (unsigned)(mr & 7) << 4;
    unsigned offA1[4];
#pragma unroll
    for (int m = 0; m < 4; ++m) offA1[m] = (unsigned)((m * 16 + mr) * 2048);

    f32x4 acc[4][4];
#pragma unroll
    for (int m = 0; m < 4; ++m)
#pragma unroll
        for (int n = 0; n < 4; ++n) acc[m][n] = (f32x4){0.f, 0.f, 0.f, 0.f};

    auto step1 = [&](int kt, f16x8 (&bu)[4], f16x8 (&bl)[4]) {
        if (kt + 1 < 32) {
#pragma unroll
            for (int n = 0; n < 4; ++n)
                bl[n] = *(const f16x8*)(bbase1[n] + (unsigned)(kt + 1) * 512u);
        }
        const unsigned ko = ((unsigned)(kt * 64) + (unsigned)kg * 16u) ^ keyA1;
        f16x8 a[4];
#pragma unroll
        for (int m = 0; m < 4; ++m)
            a[m] = *(const f16x8*)(lds + offA1[m] + ko);
        __builtin_amdgcn_s_setprio(1);
#pragma unroll
        for (int m = 0; m < 4; ++m)
#pragma unroll
            for (int n = 0; n < 4; ++n)
                acc[m][n] = MFMA16(a[m], bu[n], acc[m][n]);
        __builtin_amdgcn_s_setprio(0);
    };

#pragma unroll 1
    for (int k2 = 0; k2 < 16; ++k2) {
        step1(2 * k2, bA, bB);
        step1(2 * k2 + 1, bB, bA);
    }

    // ---------------- phase C: sigmoid -> d into LDS [64][2112B] ----------
    // byte = row*2112 + ((2 + col*2) ^ ((row>>2)&3)<<4); kg-distinct key
    __syncthreads();     // all waves done reading Xh-LDS
#pragma unroll
    for (int m = 0; m < 4; ++m)
#pragma unroll
        for (int j = 0; j < 4; ++j) {
            int row = m * 16 + fq + j;
            unsigned wkey = ((unsigned)((row >> 2) & 3)) << 4;
            char* drow = lds + row * DSTRIDE;
#pragma unroll
            for (int n = 0; n < 4; ++n) {
                int col = wid * 64 + n * 16 + mr;
                float s = acc[m][n][j];
                float dv = 1.0f / (1.0f + __expf(-s));
                *(u16*)(drow + ((2u + 2u * (unsigned)col) ^ wkey)) = f2h(dv);
            }
        }
    __syncthreads();     // d complete

    // ---------------- phase D: tree expansion (d from LDS, vector reads) ---
    u16x8 pk[4][2];
#pragma unroll
    for (int r = 0; r < 4; ++r) {
        const int lrow = wid * 4 + r;
        const char* dro = lds + lrow * DSTRIDE;
        const unsigned dkey = ((unsigned)((lrow >> 2) & 3)) << 4;
        const int l = lane;

        float prod = 1.0f;
#pragma unroll
        for (int lev = 0; lev < 6; lev++) {
            int node = (1 << lev) - 1 + (l >> (6 - lev));
            int bit  = (l >> (5 - lev)) & 1;
            float v = h2f(*(const u16*)(dro + ((2u + 2u * (unsigned)node) ^ dkey)));
            prod *= bit ? (1.0f - v) : v;
        }
        float d6 = h2f(*(const u16*)(dro + ((2u + 2u * (unsigned)(63 + l)) ^ dkey)));
        ushort2 p7 = *(const ushort2*)(dro + ((256u + 4u * (unsigned)l) ^ dkey));
        ushort4 p8 = *(const ushort4*)(dro + ((512u + 8u * (unsigned)l) ^ dkey));
        u16x8   p9 = *(const u16x8*)(dro + ((1024u + 16u * (unsigned)l) ^ dkey));
        float d7[2] = {h2f(p7.x), h2f(p7.y)};
        float d8[4] = {h2f(p8.x), h2f(p8.y), h2f(p8.z), h2f(p8.w)};
        float d9[8];
#pragma unroll
        for (int j = 0; j < 8; j++) d9[j] = h2f(p9[j]);

        u16 outv[16];
#pragma unroll
        for (int j = 0; j < 16; j++) {
            float f6 = (j >> 3) ? (1.0f - d6) : d6;
            float v7 = d7[j >> 3];  float f7 = ((j >> 2) & 1) ? (1.0f - v7) : v7;
            float v8 = d8[j >> 2];  float f8 = ((j >> 1) & 1) ? (1.0f - v8) : v8;
            float v9 = d9[j >> 1];  float f9 = (j & 1) ? (1.0f - v9) : v9;
            outv[j] = f2h(prod * f6 * f7 * f8 * f9);
        }
        pk[r][0] = (u16x8){outv[0], outv[1], outv[2], outv[3],
                           outv[4], outv[5], outv[6], outv[7]};
        pk[r][1] = (u16x8){outv[8], outv[9], outv[10], outv[11],
                           outv[12], outv[13], outv[14], outv[15]};
    }
    __syncthreads();     // all d reads done before probs overwrite

    // packed probs write, slot-XOR (kt&7): 8-way instead of 32-way conflicts
    {
        const int ktw = lane >> 1, kg0 = (lane & 1) * 2;
        const unsigned K = (unsigned)(ktw & 7);
#pragma unroll
        for (int r = 0; r < 4; ++r) {
            const int lrow = wid * 4 + r;
            const int m = lrow >> 4, mrr = lrow & 15;
            char* base = lds + (((ktw << 2) + m) << 10);
            unsigned s0 = ((unsigned)(kg0 * 16 + mrr)) ^ K;
            unsigned s1 = ((unsigned)((kg0 + 1) * 16 + mrr)) ^ K;
            *(u16x8*)(base + s0 * 16) = pk[r][0];
            *(u16x8*)(base + s1 * 16) = pk[r][1];
        }
    }
    __syncthreads();     // probs complete

    // ---------------- phase E: gemm2 barrier-free K-loop ----------------
    const u16* bbase2 = BpkL + (size_t)(wid * 4) * 16384 + (unsigned)lane * 8u;

#pragma unroll
    for (int m = 0; m < 4; ++m)
#pragma unroll
        for (int n = 0; n < 4; ++n) acc[m][n] = (f32x4){0.f, 0.f, 0.f, 0.f};

#pragma unroll
    for (int n = 0; n < 4; ++n) bA[n] = *(const f16x8*)(bbase2 + n * 16384);

    auto step2 = [&](int kt, f16x8 (&bu)[4], f16x8 (&bl)[4]) {
        if (kt + 1 < 32) {
#pragma unroll
            for (int n = 0; n < 4; ++n)
                bl[n] = *(const f16x8*)(bbase2 + n * 16384 + (unsigned)(kt + 1) * 512u);
        }
        const unsigned sl = ((unsigned)(lane ^ (kt & 7))) << 4;
        f16x8 a[4];
#pragma unroll
        for (int m = 0; m < 4; ++m)
            a[m] = *(const f16x8*)(lds + (((kt << 2) + m) << 10) + sl);
        __builtin_amdgcn_s_setprio(1);
#pragma unroll
        for (int m = 0; m < 4; ++m)
#pragma unroll
            for (int n = 0; n < 4; ++n)
                acc[m][n] = MFMA16(a[m], bu[n], acc[m][n]);
        __builtin_amdgcn_s_setprio(0);
    };

#pragma unroll 1
    for (int k2 = 0; k2 < 16; ++k2) {
        step2(2 * k2, bA, bB);
        step2(2 * k2 + 1, bB, bA);
    }

    __syncthreads();     // all probs reads done before red reuse

    // ---------------- phase F: in-register softmax (frozen) ---------------
    float* red  = (float*)lds;            // [64][16] max
    float* red2 = (float*)(lds + 4096);   // [64][16] sum

    float mx[4][4];
#pragma unroll
    for (int m = 0; m < 4; ++m)
#pragma unroll
        for (int j = 0; j < 4; ++j) {
            float v = acc[m][0][j];
#pragma unroll
            for (int n = 1; n < 4; ++n) v = fmaxf(v, acc[m][n][j]);
#pragma unroll
            for (int off = 1; off < 16; off <<= 1)
                v = fmaxf(v, __shfl_xor(v, off));
            mx[m][j] = v;
        }
    if (mr == 0) {
#pragma unroll
        for (int m = 0; m < 4; ++m)
#pragma unroll
            for (int j = 0; j < 4; ++j)
                red[(m * 16 + fq + j) * 16 + wid] = mx[m][j];
    }
    __syncthreads();
    if (t < 64) {
        float v = red[t * 16];
#pragma unroll
        for (int w = 1; w < 16; ++w) v = fmaxf(v, red[t * 16 + w]);
        red[t * 16] = v;
    }
    __syncthreads();

    float sm[4][4];
#pragma unroll
    for (int m = 0; m < 4; ++m)
#pragma unroll
        for (int j = 0; j < 4; ++j) {
            float M = red[(m * 16 + fq + j) * 16];
            float s = 0.f;
#pragma unroll
            for (int n = 0; n < 4; ++n) {
                float e = __expf(acc[m][n][j] - M);
                acc[m][n][j] = e;
                s += e;
            }
#pragma unroll
            for (int off = 1; off < 16; off <<= 1)
                s += __shfl_xor(s, off);
            sm[m][j] = s;
        }
    if (mr == 0) {
#pragma unroll
        for (int m = 0; m < 4; ++m)
#pragma unroll
            for (int j = 0; j < 4; ++j)
                red2[(m * 16 + fq + j) * 16 + wid] = sm[m][j];
    }
    __syncthreads();
    if (t < 64) {
        float v = 0.f;
#pragma unroll
        for (int w = 0; w < 16; ++w) v += red2[t * 16 + w];
        red2[t * 16] = 1.0f / v;
    }
    __syncthreads();

#pragma unroll
    for (int m = 0; m < 4; ++m)
#pragma unroll
        for (int j = 0; j < 4; ++j) {
            int grow = rb + m * 16 + fq + j;
            float inv = red2[(m * 16 + fq + j) * 16];
#pragma unroll
            for (int n = 0; n < 4; ++n) {
                int gcol = wid * 64 + n * 16 + mr;
                out[(size_t)grow * 1024 + gcol] = acc[m][n][j] * inv;
            }
        }
}

// ---------------------------------------------------------------------------
extern "C" void kernel_launch(void* const* d_in, const int* in_sizes, int n_in,
                              void* d_out, int out_size, void* d_ws, size_t ws_size,
                              hipStream_t stream) {
    const float* x  = (const float*)d_in[0];
    const float* ft = (const float*)d_in[1];
    const float* lp = (const float*)d_in[2];
    float* out = (float*)d_out;
    char* ws = (char*)d_ws;

    // ws layout: Bpk1 2Mi | BpkL 2Mi
    u16* Bpk1 = (u16*)ws;
    u16* BpkL = Bpk1 + (size_t)NPAD * DIM;

    prep_tp<<<1024, 256, 0, stream>>>(ft, Bpk1);
    prep_lt<<<1024, 256, 0, stream>>>(lp, BpkL);
    megak<<<512, 1024, 0, stream>>>(x, Bpk1, BpkL, out);
}